// Round 6
// baseline (119.096 us; speedup 1.0000x reference)
//
#include <hip/hip_runtime.h>
#include <hip/hip_cooperative_groups.h>

namespace cg = cooperative_groups;

// Fourier head: B=512, P=1024, K=64. Inputs f32, output f32 (R0-R2 triangulated).
// out[b,p] = a0/(2P) + sum_k pa[b,k]*cos(c*x[b,p]*k) + pb[b,k]*sin(c*x[b,p]*k)
//
// R3/R4: fused 1-kernel ~6.5us inside dur~72 (harness fixed cost ~65.5us:
// 256MB ws poison fill @84% HBM + restores + gaps). Fused stage B streams all
// of a+b (512KB) through every CU -> ~3.9us, structural.
// R5: 2-kernel split cut kernel work to ~2.8us but dur +12.5us -> per-graph-node
// dispatch overhead ~12us. Lesson: SINGLE DISPATCH ONLY.
// R6: same split algorithm, fused into ONE cooperative kernel with grid.sync().
// Phase1: 256 blocks (16 pc x 16 bt), each reads unique 32KB a/b slice,
// writes pw[512][16][128] partials to ws. grid.sync. Phase2: 2 rows/block,
// reduce 16 partials + Chebyshev stage C.

constexpr int PN = 1024;
constexpr int KN = 64;

__global__ __launch_bounds__(256) void fourier_coop(
    const float* __restrict__ x,
    const float* __restrict__ a,
    const float* __restrict__ bco,
    const float* __restrict__ a0,
    float* __restrict__ pw,
    float* __restrict__ out)
{
    __shared__ float xs[32][68];        // x-tile; stride 68 floats (272B, 16B
                                        // aligned) -> rows hit distinct banks
    __shared__ float spab[2][2 * KN];   // phase 2: interleaved pa/pb, 2 rows

    const int t = threadIdx.x;
    const int bid = blockIdx.x;         // 256 blocks, 1 per CU

    // ================= Phase 1: partial GEMM =================
    {
        const int pc = bid & 15;        // p-chunk: p in [64*pc, 64*pc+64)
        const int bt = bid >> 4;        // b-tile:  b in [32*bt, 32*bt+32)
        const int p0 = pc * 64;
        const int b0 = bt * 32;

        // Stage x-tile (float4 global, coalesced 256B/row-segment).
        {
            const int c = t & 15, row = t >> 4;
            #pragma unroll
            for (int h = 0; h < 2; ++h) {
                const int r = row + 16 * h;
                const float4 v = *(const float4*)(x + (size_t)(b0 + r) * PN + p0 + 4 * c);
                *(float4*)&xs[r][4 * c] = v;
            }
        }
        __syncthreads();

        // Thread (kg=t&15, bg=t>>4): k-quad 4*kg, rows 2bg, 2bg+1.
        const int kg = t & 15;
        const int bg = t >> 4;
        float sa[2][4] = {{0.f}}, sb[2][4] = {{0.f}};
        #pragma unroll 2
        for (int i4 = 0; i4 < 16; ++i4) {
            float xl[2][4];
            *(float4*)&xl[0][0] = *(const float4*)&xs[2 * bg + 0][4 * i4];
            *(float4*)&xl[1][0] = *(const float4*)&xs[2 * bg + 1][4 * i4];
            #pragma unroll
            for (int q = 0; q < 4; ++q) {
                const int p = p0 + 4 * i4 + q;
                const float4 av = *(const float4*)(a   + (size_t)p * KN + 4 * kg);
                const float4 bv = *(const float4*)(bco + (size_t)p * KN + 4 * kg);
                #pragma unroll
                for (int r = 0; r < 2; ++r) {
                    const float xv = xl[r][q];
                    sa[r][0] = fmaf(xv, av.x, sa[r][0]);
                    sa[r][1] = fmaf(xv, av.y, sa[r][1]);
                    sa[r][2] = fmaf(xv, av.z, sa[r][2]);
                    sa[r][3] = fmaf(xv, av.w, sa[r][3]);
                    sb[r][0] = fmaf(xv, bv.x, sb[r][0]);
                    sb[r][1] = fmaf(xv, bv.y, sb[r][1]);
                    sb[r][2] = fmaf(xv, bv.z, sb[r][2]);
                    sb[r][3] = fmaf(xv, bv.w, sb[r][3]);
                }
            }
        }

        // pw[b][pc][2k+{0,1}]: interleaved (pa,pb) partials, float2 stores.
        #pragma unroll
        for (int r = 0; r < 2; ++r) {
            float* dst = pw + (((size_t)(b0 + 2 * bg + r) * 16 + pc) * 128) + 8 * kg;
            #pragma unroll
            for (int j = 0; j < 4; ++j) {
                float2 v; v.x = sa[r][j]; v.y = sb[r][j];
                *(float2*)(dst + 2 * j) = v;
            }
        }
    }

    // Device-scope barrier: pw partials visible across XCDs after this.
    cg::this_grid().sync();

    // ================= Phase 2: reduce + stage C, rows 2bid, 2bid+1 ========
    {
        // Reduce 16 p-chunks for both rows: 256 sums, one per thread.
        const int row = t >> 7;          // 0/1
        const int idx = t & 127;
        const float* src = pw + (size_t)(2 * bid + row) * (16 * 128) + idx;
        float s = 0.f;
        #pragma unroll
        for (int pc = 0; pc < 16; ++pc) s += src[pc * 128];
        spab[row][idx] = s;
    }
    __syncthreads();

    const float c0 = a0[0] * (1.0f / (2.0f * (float)PN));
    const float tp = (float)(6.283185307179586 / (double)PN);  // 2*pi/P

    #pragma unroll
    for (int r = 0; r < 2; ++r) {
        const int b = 2 * bid + r;
        const float4 xv4 = ((const float4*)(x + (size_t)b * PN))[t];
        const float xv[4] = {xv4.x, xv4.y, xv4.z, xv4.w};

        float cm1[4], sm1[4], cm2[4], sm2[4], t2[4], acc[4];
        const float pa0 = spab[r][0];
        const float pa1 = spab[r][2];
        const float pb1 = spab[r][3];
        #pragma unroll
        for (int j = 0; j < 4; ++j) {
            const float th = tp * xv[j];
            float c1, s1;
            __sincosf(th, &s1, &c1);
            t2[j]  = c1 + c1;
            cm2[j] = 1.f; sm2[j] = 0.f;   // k=0
            cm1[j] = c1;  sm1[j] = s1;    // k=1
            acc[j] = fmaf(pa1, c1, fmaf(pb1, s1, c0 + pa0));
        }
        #pragma unroll 8
        for (int k = 2; k < KN; ++k) {
            const float2 pk = *(const float2*)&spab[r][2 * k];  // ds_read_b64
            #pragma unroll
            for (int j = 0; j < 4; ++j) {
                const float ck = fmaf(t2[j], cm1[j], -cm2[j]);
                const float sk = fmaf(t2[j], sm1[j], -sm2[j]);
                acc[j] = fmaf(pk.x, ck, acc[j]);
                acc[j] = fmaf(pk.y, sk, acc[j]);
                cm2[j] = cm1[j]; cm1[j] = ck;
                sm2[j] = sm1[j]; sm1[j] = sk;
            }
        }
        float4 o; o.x = acc[0]; o.y = acc[1]; o.z = acc[2]; o.w = acc[3];
        ((float4*)(out + (size_t)b * PN))[t] = o;
    }
}

extern "C" void kernel_launch(void* const* d_in, const int* in_sizes, int n_in,
                              void* d_out, int out_size, void* d_ws, size_t ws_size,
                              hipStream_t stream) {
    const float* x  = (const float*)d_in[0];
    const float* a  = (const float*)d_in[1];
    const float* b  = (const float*)d_in[2];
    const float* a0 = (const float*)d_in[3];
    float* out = (float*)d_out;
    float* pw  = (float*)d_ws;              // 512*16*128*4 = 4 MB

    void* kargs[] = {(void*)&x, (void*)&a, (void*)&b, (void*)&a0,
                     (void*)&pw, (void*)&out};
    hipLaunchCooperativeKernel(fourier_coop, dim3(256), dim3(256),
                               kargs, 0, stream);
}

// Round 7
// 77.721 us; speedup vs baseline: 1.5324x; 1.5324x over previous
//
#include <hip/hip_runtime.h>

// Fourier head: B=512, P=1024, K=64. Inputs f32, output f32 (R0-R2 triangulated).
// out[b,p] = a0/(2P) + sum_k pa[b,k]*cos(c*x[b,p]*k) + pb[b,k]*sin(c*x[b,p]*k)
//
// Journal: harness fixed cost ~65.5us (256MB ws poison fill @84% HBM + restores).
// R4 fused kernel ~6.5us (dur 72.06). R5 2-kernel: +12us/graph-node -> SINGLE
// DISPATCH ONLY. R6 coop grid.sync: kernel 44us (2% HBM, 8% VALU = idle) ->
// NO GRID SYNC. R7: stay fused; split k into 2x32 chunks and overlap chunk-1
// a/b loads (load-bound, ~273cyc/iter/CU) with chunk-0 Chebyshev (VALU) in one
// fused loop (ILP; 1 wave/SIMD has no TLP). Pack math with v_pk_fma_f32
// (CDNA4 2x f32). Pad red stride 32->34 (8-way LDS write conflict -> ~2-way).

typedef float f2 __attribute__((ext_vector_type(2)));

__device__ __forceinline__ f2 pk_fma(f2 a, f2 b, f2 c) {
    f2 d;
    asm("v_pk_fma_f32 %0, %1, %2, %3" : "=v"(d) : "v"(a), "v"(b), "v"(c));
    return d;
}
__device__ __forceinline__ f2 pk_mul(f2 a, f2 b) {
    f2 d;
    asm("v_pk_mul_f32 %0, %1, %2" : "=v"(d) : "v"(a), "v"(b));
    return d;
}

constexpr int PN = 1024;
constexpr int KN = 64;

__global__ __launch_bounds__(256) void fourier_fused(
    const float* __restrict__ x,
    const float* __restrict__ a,
    const float* __restrict__ bco,
    const float* __restrict__ a0,
    float* __restrict__ out)
{
    __shared__ float xs[2][PN];            // 8 KB
    __shared__ float red[2][2][32][34];    // 17.4 KB [ab][row][pg][k(+pad)]
    __shared__ float spab[2][64];          // [row][2k+ab], one 32-k chunk

    const int t = threadIdx.x;
    const int b0 = 2 * blockIdx.x;         // 256 blocks, 2 rows each

    // ---- Stage A: 2 x-rows -> LDS ----
    #pragma unroll
    for (int r = 0; r < 2; ++r)
        *(float4*)&xs[r][4 * t] = ((const float4*)(x + (size_t)(b0 + r) * PN))[t];
    __syncthreads();

    const int kg = t & 7;                  // k-quad within 32-k chunk
    const int pg = t >> 3;                 // 0..31

    // ================= B0: chunk 0 (cols 0..31) =================
    f2 sa01[2] = {}, sa23[2] = {}, sb01[2] = {}, sb23[2] = {};
    #pragma unroll 2
    for (int i = 0; i < 32; ++i) {
        const int p = pg + 32 * i;
        const float4 av = *(const float4*)(a   + (size_t)p * KN + 4 * kg);
        const float4 bv = *(const float4*)(bco + (size_t)p * KN + 4 * kg);
        #pragma unroll
        for (int r = 0; r < 2; ++r) {
            const float xv = xs[r][p];
            const f2 xx = {xv, xv};
            sa01[r] = pk_fma(xx, f2{av.x, av.y}, sa01[r]);
            sa23[r] = pk_fma(xx, f2{av.z, av.w}, sa23[r]);
            sb01[r] = pk_fma(xx, f2{bv.x, bv.y}, sb01[r]);
            sb23[r] = pk_fma(xx, f2{bv.z, bv.w}, sb23[r]);
        }
    }
    #pragma unroll
    for (int r = 0; r < 2; ++r) {
        *(f2*)&red[0][r][pg][4 * kg]     = sa01[r];
        *(f2*)&red[0][r][pg][4 * kg + 2] = sa23[r];
        *(f2*)&red[1][r][pg][4 * kg]     = sb01[r];
        *(f2*)&red[1][r][pg][4 * kg + 2] = sb23[r];
    }
    __syncthreads();
    if (t < 128) {                          // 2ab x 2r x 32k sums
        const int ab = (t >> 6) & 1, r = (t >> 5) & 1, k = t & 31;
        float s = 0.f;
        #pragma unroll
        for (int g = 0; g < 32; ++g) s += red[ab][r][g][k];
        spab[r][2 * k + ab] = s;
    }
    __syncthreads();

    // ---- Chebyshev state init (k=0 term folded into acc; p1 = k=1) ----
    const float c0b = a0[0] * (1.0f / (2.0f * (float)PN));
    const float tp  = (float)(6.283185307179586 / (double)PN);
    const f2 negone = {-1.f, -1.f};

    f2 p1[2][4], np2[2][4], acc[2][4], t2v[2][4];
    #pragma unroll
    for (int r = 0; r < 2; ++r) {
        const float pa0 = spab[r][0];
        #pragma unroll
        for (int j = 0; j < 4; ++j) {
            const float th = tp * xs[r][4 * t + j];
            float c1, s1;
            __sincosf(th, &s1, &c1);
            p1[r][j]  = f2{c1, s1};         // [cos k, sin k] at k=1
            np2[r][j] = f2{-1.f, 0.f};      // -[cos, sin] at k=0
            t2v[r][j] = f2{c1 + c1, c1 + c1};
            acc[r][j] = f2{c0b + pa0, 0.f}; // [cos-part, sin-part]
        }
    }

    // ====== Fused: B1 loads (cols 32..63) overlapped with C0 (k=1..31) ======
    f2 ta01[2] = {}, ta23[2] = {}, tb01[2] = {}, tb23[2] = {};
    {   // i = 0 peeled: loads + B-FMA only
        const int p = pg;
        const float4 av = *(const float4*)(a   + (size_t)p * KN + 32 + 4 * kg);
        const float4 bv = *(const float4*)(bco + (size_t)p * KN + 32 + 4 * kg);
        #pragma unroll
        for (int r = 0; r < 2; ++r) {
            const float xv = xs[r][p];
            const f2 xx = {xv, xv};
            ta01[r] = pk_fma(xx, f2{av.x, av.y}, ta01[r]);
            ta23[r] = pk_fma(xx, f2{av.z, av.w}, ta23[r]);
            tb01[r] = pk_fma(xx, f2{bv.x, bv.y}, tb01[r]);
            tb23[r] = pk_fma(xx, f2{bv.z, bv.w}, tb23[r]);
        }
    }
    #pragma unroll 2
    for (int i = 1; i < 32; ++i) {
        const int p = pg + 32 * i;
        const float4 av = *(const float4*)(a   + (size_t)p * KN + 32 + 4 * kg);
        const float4 bv = *(const float4*)(bco + (size_t)p * KN + 32 + 4 * kg);
        // C0 k-step (k = i): independent of the loads above -> fills load shadow
        #pragma unroll
        for (int r = 0; r < 2; ++r) {
            const f2 coef = *(const f2*)&spab[r][2 * i];   // wave-uniform bcast
            #pragma unroll
            for (int j = 0; j < 4; ++j) {
                acc[r][j] = pk_fma(coef, p1[r][j], acc[r][j]);
                const f2 pn = pk_fma(t2v[r][j], p1[r][j], np2[r][j]);
                np2[r][j] = pk_mul(p1[r][j], negone);
                p1[r][j]  = pn;
            }
        }
        #pragma unroll
        for (int r = 0; r < 2; ++r) {
            const float xv = xs[r][p];
            const f2 xx = {xv, xv};
            ta01[r] = pk_fma(xx, f2{av.x, av.y}, ta01[r]);
            ta23[r] = pk_fma(xx, f2{av.z, av.w}, ta23[r]);
            tb01[r] = pk_fma(xx, f2{bv.x, bv.y}, tb01[r]);
            tb23[r] = pk_fma(xx, f2{bv.z, bv.w}, tb23[r]);
        }
    }
    __syncthreads();                        // all C0 spab reads done
    #pragma unroll
    for (int r = 0; r < 2; ++r) {
        *(f2*)&red[0][r][pg][4 * kg]     = ta01[r];
        *(f2*)&red[0][r][pg][4 * kg + 2] = ta23[r];
        *(f2*)&red[1][r][pg][4 * kg]     = tb01[r];
        *(f2*)&red[1][r][pg][4 * kg + 2] = tb23[r];
    }
    __syncthreads();
    if (t < 128) {
        const int ab = (t >> 6) & 1, r = (t >> 5) & 1, k = t & 31;
        float s = 0.f;
        #pragma unroll
        for (int g = 0; g < 32; ++g) s += red[ab][r][g][k];
        spab[r][2 * k + ab] = s;
    }
    __syncthreads();

    // ================= C1 tail: k = 32..63 =================
    #pragma unroll 4
    for (int kk = 0; kk < 32; ++kk) {
        #pragma unroll
        for (int r = 0; r < 2; ++r) {
            const f2 coef = *(const f2*)&spab[r][2 * kk];
            #pragma unroll
            for (int j = 0; j < 4; ++j) {
                acc[r][j] = pk_fma(coef, p1[r][j], acc[r][j]);
                const f2 pn = pk_fma(t2v[r][j], p1[r][j], np2[r][j]);
                np2[r][j] = pk_mul(p1[r][j], negone);
                p1[r][j]  = pn;
            }
        }
    }

    #pragma unroll
    for (int r = 0; r < 2; ++r) {
        float4 o;
        o.x = acc[r][0].x + acc[r][0].y;
        o.y = acc[r][1].x + acc[r][1].y;
        o.z = acc[r][2].x + acc[r][2].y;
        o.w = acc[r][3].x + acc[r][3].y;
        ((float4*)(out + (size_t)(b0 + r) * PN))[t] = o;
    }
}

extern "C" void kernel_launch(void* const* d_in, const int* in_sizes, int n_in,
                              void* d_out, int out_size, void* d_ws, size_t ws_size,
                              hipStream_t stream) {
    const float* x  = (const float*)d_in[0];
    const float* a  = (const float*)d_in[1];
    const float* b  = (const float*)d_in[2];
    const float* a0 = (const float*)d_in[3];
    float* out = (float*)d_out;

    fourier_fused<<<dim3(256), dim3(256), 0, stream>>>(x, a, b, a0, out);
}

// Round 8
// 71.199 us; speedup vs baseline: 1.6727x; 1.0916x over previous
//
#include <hip/hip_runtime.h>

// Fourier head: B=512, P=1024, K=64.
// out[b,p] = a0/(2P) + sum_k pa[b,k]*cos(c*x[b,p]*k) + pb[b,k]*sin(c*x[b,p]*k)
// pa = x @ a, pb = x @ b, c = 2*pi/P.  Inputs f32, output f32 (R0-R2).
//
// Journal:
//  - Harness fixed cost ~65.5us/call (256MB d_ws poison fill @84% HBM +
//    input restores + inter-dispatch gaps). Kernel-side floor ~4us ->
//    practical dur floor ~69.5-70us.
//  - R4 (this code): dur 72.06, kernel ~6.5us. BEST.
//  - R5 2-kernel split: +12us per graph node. SINGLE DISPATCH ONLY.
//  - R6 cooperative grid.sync: 44us kernel, ~40us idle. NO GRID SYNC.
//  - R7 pk-asm ILP overlap: kernel ~12us. Inline v_pk_* asm defeats the
//    compiler's register allocation + load scheduling. PLAIN fmaf ONLY.
// This is the exact R4 kernel, reverted.

constexpr int PN = 1024;
constexpr int KN = 64;
constexpr int ROWS = 2;   // rows/block; grid = 256 = #CUs -> stage B reads
                          // a+b (512KB) once per block: 128MB L2 aggregate.

__global__ __launch_bounds__(256) void fourier_fused(
    const float* __restrict__ x,
    const float* __restrict__ a,
    const float* __restrict__ bco,
    const float* __restrict__ a0,
    float* __restrict__ out)
{
    __shared__ float xs[ROWS][PN];           // 8 KB
    __shared__ float red[2][ROWS][16][KN];   // 16 KB
    __shared__ float spab[ROWS][2 * KN];     // 1 KB, pa/pb interleaved

    const int t = threadIdx.x;
    const int b0 = blockIdx.x * ROWS;

    // ---- Stage A: ROWS x-rows -> LDS (float4, 16B/lane coalesced) ----
    #pragma unroll
    for (int r = 0; r < ROWS; ++r) {
        float4 v = ((const float4*)(x + (size_t)(b0 + r) * PN))[t];
        xs[r][4 * t + 0] = v.x;
        xs[r][4 * t + 1] = v.y;
        xs[r][4 * t + 2] = v.z;
        xs[r][4 * t + 3] = v.w;
    }
    __syncthreads();

    // ---- Stage B: pa[r][k] = sum_p xs[r][p]*a[p,k]; pb likewise ----
    // 256 threads = 16 k-groups (float4 along K) x 16 p-groups.
    // One wave's loads cover 1KB contiguous (4 full K-rows), coalesced.
    {
        const int kg = t & 15;               // k = 4*kg + j
        const int pg = t >> 4;               // p = pg + 16*i
        float sa[ROWS][4] = {};
        float sb[ROWS][4] = {};
        #pragma unroll 4
        for (int i = 0; i < 64; ++i) {
            const int p = pg + 16 * i;
            const float4 av = *(const float4*)(a   + p * KN + 4 * kg);
            const float4 bv = *(const float4*)(bco + p * KN + 4 * kg);
            #pragma unroll
            for (int r = 0; r < ROWS; ++r) {
                const float xv = xs[r][p];
                sa[r][0] = fmaf(xv, av.x, sa[r][0]);
                sa[r][1] = fmaf(xv, av.y, sa[r][1]);
                sa[r][2] = fmaf(xv, av.z, sa[r][2]);
                sa[r][3] = fmaf(xv, av.w, sa[r][3]);
                sb[r][0] = fmaf(xv, bv.x, sb[r][0]);
                sb[r][1] = fmaf(xv, bv.y, sb[r][1]);
                sb[r][2] = fmaf(xv, bv.z, sb[r][2]);
                sb[r][3] = fmaf(xv, bv.w, sb[r][3]);
            }
        }
        #pragma unroll
        for (int r = 0; r < ROWS; ++r) {
            #pragma unroll
            for (int j = 0; j < 4; ++j) {
                red[0][r][pg][4 * kg + j] = sa[r][j];
                red[1][r][pg][4 * kg + j] = sb[r][j];
            }
        }
    }
    __syncthreads();

    // ---- Reduce 16 p-groups: 2*ROWS*64 = 256 sums, one per thread ----
    {
        const int which = t >> 7;            // 0: pa, 1: pb
        const int r = (t >> 6) & (ROWS - 1);
        const int k = t & 63;
        float s = 0.f;
        #pragma unroll
        for (int pg = 0; pg < 16; ++pg) s += red[which][r][pg][k];
        spab[r][2 * k + which] = s;          // stride-2: 2-way bank alias, free
    }
    __syncthreads();

    // ---- Stage C: Chebyshev recurrence, 4 points/thread/row ----
    // c_k = 2c1*c_{k-1} - c_{k-2}; s_k likewise. 4 FMA per k per point.
    const float c0 = a0[0] * (1.0f / (2.0f * (float)PN));
    const float tp = (float)(6.283185307179586 / (double)PN);  // 2*pi/P

    #pragma unroll
    for (int r = 0; r < ROWS; ++r) {
        float cm1[4], sm1[4], cm2[4], sm2[4], t2[4], acc[4];
        const float pa0 = spab[r][0];
        const float pa1 = spab[r][2];
        const float pb1 = spab[r][3];
        #pragma unroll
        for (int j = 0; j < 4; ++j) {
            const float th = tp * xs[r][4 * t + j];
            float c1, s1;
            __sincosf(th, &s1, &c1);
            t2[j]  = c1 + c1;
            cm2[j] = 1.f; sm2[j] = 0.f;      // k=0
            cm1[j] = c1;  sm1[j] = s1;       // k=1
            acc[j] = fmaf(pa1, c1, fmaf(pb1, s1, c0 + pa0));
        }
        #pragma unroll 8
        for (int k = 2; k < KN; ++k) {
            const float2 pk = *(const float2*)&spab[r][2 * k];  // ds_read_b64
            #pragma unroll
            for (int j = 0; j < 4; ++j) {
                const float ck = fmaf(t2[j], cm1[j], -cm2[j]);
                const float sk = fmaf(t2[j], sm1[j], -sm2[j]);
                acc[j] = fmaf(pk.x, ck, acc[j]);
                acc[j] = fmaf(pk.y, sk, acc[j]);
                cm2[j] = cm1[j]; cm1[j] = ck;
                sm2[j] = sm1[j]; sm1[j] = sk;
            }
        }
        float4 o; o.x = acc[0]; o.y = acc[1]; o.z = acc[2]; o.w = acc[3];
        ((float4*)(out + (size_t)(b0 + r) * PN))[t] = o;
    }
}

extern "C" void kernel_launch(void* const* d_in, const int* in_sizes, int n_in,
                              void* d_out, int out_size, void* d_ws, size_t ws_size,
                              hipStream_t stream) {
    const float* x  = (const float*)d_in[0];
    const float* a  = (const float*)d_in[1];
    const float* b  = (const float*)d_in[2];
    const float* a0 = (const float*)d_in[3];
    float* out = (float*)d_out;

    const int nblocks = (out_size / PN) / ROWS;  // = 256
    fourier_fused<<<dim3(nblocks), dim3(256), 0, stream>>>(x, a, b, a0, out);
}